// Round 14
// baseline (6914.214 us; speedup 1.0000x reference)
//
#include <hip/hip_runtime.h>
#include <hip/hip_bf16.h>

// DeepLSTM on MI355X — R18: per-wave split-phase sync (zero block barriers in the loop).
//   R17 post-mortem: split-phase publish hid the flag round trip -> 6.93->6.22ms (WIN).
//   Sharing-graph audit: wave w of every block touches ONLY slab w (h0/h1/h2 loads AND
//   stores); bq is read-only after init -> the 4 waves share NOTHING in the steady loop,
//   yet R17 pays 2 __syncthreads (full 4-wave vmcnt drains) + 2 s_barrier joins per step,
//   serializing all waves to the slowest at 4 points/step.
//   R18: flags become per-wave (4x32 for A and B). pub = own-wave vmcnt(0) + lane0
//   agent store of flag[w*32+rank]; wait = poll own 32 same-slab flags + buffer_inv.
//   No block-wide sync in the loop: waves drift, jitter absorbs per-wave, polls overlap
//   other waves' compute. Hazard coverage identical to R17, finer granularity.
// Superstep s computes S0(t=s), S1(t=s-1), S2(t=s-2); reads parity s^1, writes parity s.

typedef __attribute__((ext_vector_type(8))) short short8;
typedef __attribute__((ext_vector_type(4))) float f32x4;
typedef unsigned short u16;
typedef unsigned int u32;

#define TSEQ 1000
#define NBLK 32
#define GRID_REC 256
#define NHELP (GRID_REC - NBLK)

// ws layout (bytes). Sync slot (per chunk, stride 6144): election @+0,
// flagA @+3072 (4x32 u32 = 512B), flagB @+3584 (4x32 u32).
#define O_FLAG 0L
#define O_SYNC 512L
#define O_H    1573376L  // h[3][2][4][8][64][8] bf16 = 196608 (fragment order)
#define O_C    1769984L  // c_save[3][64][256] f32 = 196608
#define O_BPA  1966592L  // packed phase-A B: 192 tiles * 8 ks * 64 lanes * 16B
#define O_BPR  3539456L  // packed rec B: 32 rank * 80 fb * 64 lanes * 16B
#define O_AX   6160896L  // Ax: single buffer (1000 t) or 2 chunked buffers ([t][3][32][64*32])

__device__ __forceinline__ u16 f2b(float v) {
    __hip_bfloat16 h = __float2bfloat16(v);
    u16 u; __builtin_memcpy(&u, &h, 2); return u;
}
__device__ __forceinline__ float b2f(u16 u) {
    __hip_bfloat16 h; __builtin_memcpy(&h, &u, 2); return __bfloat162float(h);
}
__device__ __forceinline__ float rdw(const void* p, long i, int isbf) {
    return isbf ? b2f(((const u16*)p)[i]) : ((const float*)p)[i];
}
__device__ __forceinline__ float sigm(float x) { return 1.0f / (1.0f + __expf(-x)); }
__device__ __forceinline__ float tanh_(float x) { return 1.0f - 2.0f / (1.0f + __expf(2.0f * x)); }
__device__ __forceinline__ f32x4 mfma16(short8 a, short8 b, f32x4 c) {
    return __builtin_amdgcn_mfma_f32_16x16x32_bf16(a, b, c, 0, 0, 0);
}

// ---------- dtype detect ----------
__global__ void k_detect(const u32* __restrict__ embw, int* flag) {
    __shared__ int cnt[256];
    int tid = threadIdx.x, c = 0;
    for (int i = 0; i < 16; ++i) {
        u32 w = embw[tid * 16 + i];
        u32 e = (w >> 7) & 0xFF;
        c += (e >= 110 && e <= 126) ? 1 : 0;
    }
    cnt[tid] = c; __syncthreads();
    for (int s = 128; s > 0; s >>= 1) { if (tid < s) cnt[tid] += cnt[tid + s]; __syncthreads(); }
    if (tid == 0) flag[0] = (cnt[0] > 2048) ? 1 : 0;
}

// ---------- pack phase-A B ----------
__global__ void k_pack_a(const void* W0x, const void* W1x, const void* W2x, void* wsv) {
    char* ws = (char*)wsv;
    int isbf = *(const int*)(ws + O_FLAG);
    int l = threadIdx.x & 63, w = threadIdx.x >> 6;
    int gid = blockIdx.x * 4 + w;          // 0..1535 = tile*8 + ks
    int tile = gid >> 3, ks = gid & 7;
    int L = tile >> 6, wi = tile & 63, bk = wi >> 1, half = wi & 1;
    int n16 = l & 15, g = half * 2 + (n16 >> 3), u = n16 & 7;
    int n = g * 256 + bk * 8 + u;
    const void* W = (L == 0) ? W0x : ((L == 1) ? W1x : W2x);
    union { u16 us[8]; short8 v; } tmp;
#pragma unroll
    for (int j = 0; j < 8; ++j) {
        int k = ks * 32 + (l >> 4) * 8 + j;
        tmp.us[j] = f2b(rdw(W, (long)k * 1024 + n, isbf));
    }
    ((short8*)(ws + O_BPA))[(long)(tile * 8 + ks) * 64 + l] = tmp.v;
}

// ---------- pack recurrent B ----------
__global__ void k_pack_r(const void* W0h, const void* W1x, const void* W1h,
                         const void* W2x, const void* W2h, void* wsv) {
    char* ws = (char*)wsv;
    int isbf = *(const int*)(ws + O_FLAG);
    int l = threadIdx.x & 63, w = threadIdx.x >> 6;
    int gid = blockIdx.x * 4 + w;          // 0..2559 = rank*80 + fb
    int bk = gid / 80, fb = gid % 80;
    int s, nt, ks;
    if (fb < 16) { s = 0; nt = fb >> 3; ks = fb & 7; }
    else if (fb < 48) { s = 1; int f = fb - 16; nt = f >> 4; ks = f & 15; }
    else { s = 2; int f = fb - 48; nt = f >> 4; ks = f & 15; }
    int n16 = l & 15, g = nt * 2 + (n16 >> 3), u = n16 & 7;
    int n = g * 256 + bk * 8 + u;
    union { u16 us[8]; short8 v; } tmp;
#pragma unroll
    for (int j = 0; j < 8; ++j) {
        int k = ks * 32 + (l >> 4) * 8 + j;
        float v;
        if (s == 0) v = rdw(W0h, (long)k * 1024 + n, isbf);
        else if (s == 1) v = (k < 256) ? rdw(W1x, (long)(256 + k) * 1024 + n, isbf)
                                       : rdw(W1h, (long)(k - 256) * 1024 + n, isbf);
        else v = (k < 256) ? rdw(W2x, (long)(256 + k) * 1024 + n, isbf)
                           : rdw(W2h, (long)(k - 256) * 1024 + n, isbf);
        tmp.us[j] = f2b(v);
    }
    ((short8*)(ws + O_BPR))[(long)bk * 80 * 64 + (long)fb * 64 + l] = tmp.v;
}

// ---------- x-GEMM tile: 64 batch rows x 256 gate cols at timestep t ----------
// Output layout (per t): [L(3)][rank(32)][row(64)*32 + half*16 + n16]  (4KB blocks)
__device__ __forceinline__ void gemm_tile(const int* __restrict__ ids, const void* __restrict__ emb,
    const void* b0, const void* b1, const void* b2, const short8* __restrict__ bpa,
    int isbf, int seg, int t, u16* __restrict__ axp) {
    int tid = threadIdx.x, l = tid & 63, w = tid >> 6;
    int n16 = l & 15, kg = l >> 4;
    short8 a[4][8];
#pragma unroll
    for (int mt = 0; mt < 4; ++mt) {
        int b = mt * 16 + n16;
        long id = ids[b * TSEQ + t];
        if (isbf) {
            const u16* ep = (const u16*)emb + id * 256;
#pragma unroll
            for (int ks = 0; ks < 8; ++ks)
                a[mt][ks] = *(const short8*)(ep + ks * 32 + kg * 8);
        } else {
            const float* ep = (const float*)emb + id * 256;
#pragma unroll
            for (int ks = 0; ks < 8; ++ks) {
                f32x4 v0 = *(const f32x4*)(ep + ks * 32 + kg * 8);
                f32x4 v1 = *(const f32x4*)(ep + ks * 32 + kg * 8 + 4);
                union { u16 us[8]; short8 v; } tmp;
#pragma unroll
                for (int j = 0; j < 4; ++j) { tmp.us[j] = f2b(v0[j]); tmp.us[4 + j] = f2b(v1[j]); }
                a[mt][ks] = tmp.v;
            }
        }
    }
#pragma unroll
    for (int nt = 0; nt < 4; ++nt) {
        int tile = seg * 16 + w * 4 + nt;
        f32x4 acc[4];
#pragma unroll
        for (int mt = 0; mt < 4; ++mt) acc[mt] = (f32x4){0.f, 0.f, 0.f, 0.f};
#pragma unroll
        for (int ks = 0; ks < 8; ++ks) {
            short8 bb = bpa[(long)(tile * 8 + ks) * 64 + l];
#pragma unroll
            for (int mt = 0; mt < 4; ++mt) acc[mt] = mfma16(a[mt][ks], bb, acc[mt]);
        }
        int L = tile >> 6, wi = tile & 63, bkk = wi >> 1, half = wi & 1;
        int g = half * 2 + (n16 >> 3), u = n16 & 7;
        const void* bias = (L == 0) ? b0 : ((L == 1) ? b1 : b2);
        float bv = rdw(bias, g * 256 + bkk * 8 + u, isbf);
        long base = (long)(L * 32 + bkk) * 2048 + half * 16 + n16;
#pragma unroll
        for (int mt = 0; mt < 4; ++mt)
#pragma unroll
            for (int i = 0; i < 4; ++i) {
                int row = mt * 16 + kg * 4 + i;
                axp[base + (long)row * 32] = f2b(acc[mt][i] + bv);
            }
    }
}

__global__ __launch_bounds__(256, 1) void k_gemm_x(
    const int* __restrict__ ids, const void* __restrict__ emb,
    const void* b0, const void* b1, const void* b2, void* wsv, int t0) {
    char* ws = (char*)wsv;
    int isbf = *(const int*)(ws + O_FLAG);
    const short8* bpa = (const short8*)(ws + O_BPA);
    u16* ax = (u16*)(ws + O_AX);   // buffer 0
    gemm_tile(ids, emb, b0, b1, b2, bpa, isbf, blockIdx.x, t0 + blockIdx.y,
              ax + (long)blockIdx.y * 196608);
}

// ---------- per-wave split-phase flags (agent-scope protocol, R8/R10-proven) ----------
// pub: this wave drains its own vmcnt (h-slab stores ack'd by L2), lane0 publishes
// flag[w*32+rank]. No block-wide sync — wave w's slab is touched only by wave w.
// wait: this wave polls its 32 same-slab flags, then L1-invalidates (acquire).
__device__ __forceinline__ void wflag_pub(u32* f, int idx, u32 p, int l) {
    asm volatile("s_waitcnt vmcnt(0)" ::: "memory");
    if (l == 0)
        __hip_atomic_store(f + idx, p, __ATOMIC_RELAXED, __HIP_MEMORY_SCOPE_AGENT);
}
__device__ __forceinline__ void wflag_wait(u32* f, int base, u32 p, int l) {
    u32* my = f + base + (l & 31);
    for (int it = 0; it < (1 << 20); ++it) {
        u32 v = __hip_atomic_load(my, __ATOMIC_RELAXED, __HIP_MEMORY_SCOPE_AGENT);
        if (__all((int)(v >= p))) break;
    }
    asm volatile("buffer_inv" ::: "memory");
}

// gate math, unified transcendentals (R15, proven). own lanes (n16<8): g0=i, g1=f.
// partner: g0=j, g1=o. Partner lanes compute tanh(j)/sigm(o) themselves; shfl RESULTS.
__device__ __forceinline__ void gate_update(f32x4 acc0, f32x4 acc1,
    const u32* ax0, const u32* ax1, float* cst, u16* hc, int hoff, bool own) {
    float A0 = own ? -1.0f : 2.0f;     // own: sigm(i)  partner: tanh(j)
    float C1 = own ? 1.0f : -2.0f;
    float C0 = own ? 0.0f : 1.0f;
#pragma unroll
    for (int i = 0; i < 4; ++i) {
        float g0 = acc0[i] + b2f((u16)ax0[i]);
        float g1 = acc1[i] + b2f((u16)ax1[i]);
        float v0 = C1 * (1.0f / (1.0f + __expf(A0 * g0))) + C0;  // sigm(i) | tanh(j)
        float v1 = 1.0f / (1.0f + __expf(-g1));                  // sigm(f) | sigm(o)
        float tj = __shfl_xor(v0, 8, 64);   // own receives tanh(j)
        float so = __shfl_xor(v1, 8, 64);   // own receives sigm(o)
        float cn = v1 * cst[i] + v0 * tj;   // own: sigm(f)*c + sigm(i)*tanh(j)
        float hn = so * tanh_(cn);          // own: sigm(o)*tanh(cn)
        cst[i] = own ? cn : 0.0f;
        if (own) hc[hoff + i * 8] = f2b(hn);
    }
}

// issue one stage's Ax slice as raw u16 loads (consumed next superstep)
__device__ __forceinline__ void loadax_raw(u32 dst[2][4], const u16* axs, int n16, int w, int kg) {
#pragma unroll
    for (int i = 0; i < 4; ++i) {
        int row = w * 16 + kg * 4 + i;
        dst[0][i] = axs[row * 32 + n16];
        dst[1][i] = axs[row * 32 + 16 + n16];
    }
}

// load one 16-row h slab (fragment order -> fully coalesced: lane l reads +l*8)
__device__ __forceinline__ void ldslab(short8 dst[8], const u16* hb, int w, int l) {
#pragma unroll
    for (int ks = 0; ks < 8; ++ks)
        dst[ks] = *(const short8*)(hb + w * 4096 + ks * 512 + l * 8);
}

// MFMA accumulation, B from LDS
__device__ __forceinline__ void acc8r(const short8 a[8], const short8* bq,
    int i0, int i1, int l, f32x4& a0, f32x4& a1) {
#pragma unroll
    for (int ks = 0; ks < 8; ++ks) {
        a0 = mfma16(a[ks], bq[(i0 + ks) * 64 + l], a0);
        a1 = mfma16(a[ks], bq[(i1 + ks) * 64 + l], a1);
    }
}

__global__ __launch_bounds__(256, 1) void k_rec(
    const int* __restrict__ ids, const void* __restrict__ emb,
    const void* b0, const void* b1, const void* b2,
    void* wsv, void* outv, int chunk, int t0, int tc, int t0n, int tcn,
    long axstride, int first, int last) {
    __shared__ short8 bq[4096];
    __shared__ int sh_role, sh_rank;
    char* ws = (char*)wsv;
    int tid = threadIdx.x, l = tid & 63, w = tid >> 6;
    int isbf = *(const int*)(ws + O_FLAG);
    char* slot = ws + O_SYNC + (long)chunk * 6144;
    int* syn = (int*)slot;
    u32* flagA = (u32*)(slot + 3072);   // [4 waves][32 ranks]
    u32* flagB = (u32*)(slot + 3584);   // [4 waves][32 ranks]
    // ---- census & election (once per dispatch; agent atomics OK here) ----
    if (tid == 0) {
        int xcc;
        asm volatile("s_getreg_b32 %0, hwreg(HW_REG_XCC_ID, 0, 8)" : "=s"(xcc));
        xcc &= 7;
        int r = __hip_atomic_fetch_add(syn + 2 + xcc, 1, __ATOMIC_RELAXED, __HIP_MEMORY_SCOPE_AGENT);
        int role = 1, rank = -1;
        if (r < NBLK) {
            if (r == NBLK - 1) {
                int exp = 0;
                __hip_atomic_compare_exchange_strong(syn + 10, &exp, xcc + 1,
                    __ATOMIC_RELAXED, __ATOMIC_RELAXED, __HIP_MEMORY_SCOPE_AGENT);
            }
            int wv;
            while ((wv = __hip_atomic_load(syn + 10, __ATOMIC_RELAXED, __HIP_MEMORY_SCOPE_AGENT)) == 0)
                __builtin_amdgcn_s_sleep(8);
            if (wv == xcc + 1) { role = 0; rank = r; }
        }
        if (role) rank = __hip_atomic_fetch_add(syn + 11, 1, __ATOMIC_RELAXED, __HIP_MEMORY_SCOPE_AGENT);
        sh_role = role; sh_rank = rank;
    }
    __syncthreads();
    int role = sh_role, rank = sh_rank;

    if (role) {   // ---- helper: next chunk's x-GEMM (chunked fallback mode only) ----
        asm volatile("s_setprio 0");
        if (tcn > 0) {
            const short8* bpa = (const short8*)(ws + O_BPA);
            u16* axn = (u16*)(ws + O_AX) + (long)((chunk + 1) & 1) * axstride;
            for (int job = rank; job < 12 * tcn; job += NHELP) {
                int seg = job % 12, tl = job / 12;
                gemm_tile(ids, emb, b0, b1, b2, bpa, isbf, seg, t0n + tl,
                          axn + (long)tl * 196608);
            }
        }
        return;
    }
    asm volatile("s_setprio 3");
    // ---- worker ----
    const short8* bpr = (const short8*)(ws + O_BPR) + (long)rank * 80 * 64;
#pragma unroll
    for (int i = 0; i < 16; ++i) bq[i * 256 + tid] = bpr[16 * 64 + i * 256 + tid];
    short8 w0a[8], w0b[8];
#pragma unroll
    for (int ks = 0; ks < 8; ++ks) { w0a[ks] = bpr[ks * 64 + l]; w0b[ks] = bpr[(8 + ks) * 64 + l]; }
    u16* hbuf = (u16*)(ws + O_H);
    float* csave = (float*)(ws + O_C);
    const u16* axc = (const u16*)(ws + O_AX) + (long)(chunk & 1) * axstride;
    int n16 = l & 15, kg = l >> 4;
    int hu = rank * 8 + (n16 & 7);
    bool own = n16 < 8;
    // fragment-layout store addressing
    int gbase = w * 4096 + (rank >> 2) * 512;          // [slab=w][ks_w=rank>>2]
    int hoff = (rank & 3) * 128 + kg * 32 + (n16 & 7); // lane' * 8 + j
    int fbase = w * 32;                                // this wave's flag row
    float c0[4], c1[4], c2[4];
#pragma unroll
    for (int i = 0; i < 4; ++i) {
        int row = w * 16 + kg * 4 + i;
        if (first || !own) { c0[i] = 0.f; c1[i] = 0.f; c2[i] = 0.f; }
        else {
            c0[i] = csave[(0 * 64 + row) * 256 + hu];
            c1[i] = csave[(1 * 64 + row) * 256 + hu];
            c2[i] = csave[(2 * 64 + row) * 256 + hu];
        }
    }
    __syncthreads();                                   // bq visible to all waves (once)
    u32 lph = 0;
    const int sEnd = t0 + tc + 2;
    const int tEnd = t0 + tc;
    // ---- distance-1 pipelined Ax prefetch: RAW bf16 bits in pxA/pxB ping-pong ----
    u32 pxA[3][2][4], pxB[3][2][4];
    if (tc > 0) loadax_raw(pxA[0], axc + (long)rank * 2048, n16, w, kg);   // s=t0: only S0 active

// Per superstep, per WAVE (no intra-block sync):
//   P1: ldslab h0(slab w); S0 MFMA + gates + h0 stores; pub flagA[w][rank]=lph+1
//   P2: issue Ax prefetch; wait flagB[w][*]>=lph (pub'd end of prev step, 1 phase in
//       flight); ldslab h1,h2; S1+S2 MFMA + gates + stores; pub flagB[w][rank]=lph+1
//   P3: wait flagA[w][*]>=lph+1 (pub'd ~2/3 step ago) [skip after last step]
#define SSTEP(CUR, NXT, S)                                                                         \
    do {                                                                                           \
        int par = (S) & 1, prv = par ^ 1;                                                          \
        const u16* h0p = hbuf + (0 * 2 + prv) * 16384; u16* h0c = hbuf + (0 * 2 + par) * 16384;    \
        const u16* h1p = hbuf + (1 * 2 + prv) * 16384; u16* h1c = hbuf + (1 * 2 + par) * 16384;    \
        const u16* h2p = hbuf + (2 * 2 + prv) * 16384; u16* h2c = hbuf + (2 * 2 + par) * 16384;    \
        bool l0 = (S) < tEnd, l1 = (S) > t0 && (S) <= tEnd, l2 = (S) > t0 + 1;                     \
        short8 a0r[8], a1r[8], a2r[8];                                                             \
        if (l0 || l1) ldslab(a0r, h0p, w, l);                                                      \
        if (l0) {                                                                                  \
            f32x4 A00 = {0.f, 0.f, 0.f, 0.f}, A01 = A00;                                           \
            _Pragma("unroll")                                                                      \
            for (int ks = 0; ks < 8; ++ks) {                                                       \
                A00 = mfma16(a0r[ks], w0a[ks], A00); A01 = mfma16(a0r[ks], w0b[ks], A01);          \
            }                                                                                      \
            gate_update(A00, A01, CUR[0][0], CUR[0][1], c0, h0c + gbase, hoff, own);               \
        }                                                                                          \
        wflag_pub(flagA, fbase + rank, lph + 1, l);                                                \
        int q = (S) + 1;                                                                           \
        if (q < sEnd) {                                                                            \
            if (q < tEnd)                                                                          \
                loadax_raw(NXT[0], axc + (long)(q - t0) * 196608 + (long)rank * 2048, n16, w, kg); \
            if (q > t0 && q <= tEnd)                                                               \
                loadax_raw(NXT[1], axc + (long)(q - 1 - t0) * 196608 + (long)(32 + rank) * 2048, n16, w, kg); \
            if (q > t0 + 1)                                                                        \
                loadax_raw(NXT[2], axc + (long)(q - 2 - t0) * 196608 + (long)(64 + rank) * 2048, n16, w, kg); \
        }                                                                                          \
        wflag_wait(flagB, fbase, lph, l);                                                          \
        if (l1 || l2) ldslab(a1r, h1p, w, l);                                                      \
        if (l2)       ldslab(a2r, h2p, w, l);                                                      \
        if (l1) {                                                                                  \
            f32x4 A10 = {0.f, 0.f, 0.f, 0.f}, A11 = A10;                                           \
            acc8r(a0r, bq, 0, 16, l, A10, A11); acc8r(a1r, bq, 8, 24, l, A10, A11);                \
            gate_update(A10, A11, CUR[1][0], CUR[1][1], c1, h1c + gbase, hoff, own);               \
        }                                                                                          \
        if (l2) {                                                                                  \
            f32x4 A20 = {0.f, 0.f, 0.f, 0.f}, A21 = A20;                                           \
            acc8r(a1r, bq, 32, 48, l, A20, A21); acc8r(a2r, bq, 40, 56, l, A20, A21);              \
            gate_update(A20, A21, CUR[2][0], CUR[2][1], c2, h2c + gbase, hoff, own);               \
        }                                                                                          \
        wflag_pub(flagB, fbase + rank, lph + 1, l);                                                \
        ++lph;                                                                                     \
        if ((S) + 1 < sEnd) wflag_wait(flagA, fbase, lph, l);                                      \
    } while (0)

    for (int s = t0; s < sEnd; ) {
        SSTEP(pxA, pxB, s); ++s; if (s >= sEnd) break;
        SSTEP(pxB, pxA, s); ++s;
    }
#undef SSTEP

    if (own) {
#pragma unroll
        for (int i = 0; i < 4; ++i) {
            int row = w * 16 + kg * 4 + i;
            csave[(0 * 64 + row) * 256 + hu] = c0[i];
            csave[(1 * 64 + row) * 256 + hu] = c1[i];
            csave[(2 * 64 + row) * 256 + hu] = c2[i];
        }
        if (last) {
            int f0 = (TSEQ - 1) & 1, f1 = TSEQ & 1, f2 = (TSEQ + 1) & 1;
#pragma unroll
            for (int i = 0; i < 4; ++i) {
                int row = w * 16 + kg * 4 + i;
                float h0v = b2f(hbuf[(0 * 2 + f0) * 16384 + gbase + hoff + i * 8]);
                float h1v = b2f(hbuf[(1 * 2 + f1) * 16384 + gbase + hoff + i * 8]);
                float h2v = b2f(hbuf[(2 * 2 + f2) * 16384 + gbase + hoff + i * 8]);
                if (isbf) {
                    u16* o = (u16*)outv;
                    o[row * 1536 + 0 + hu] = f2b(c0[i]);
                    o[row * 1536 + 256 + hu] = f2b(h0v);
                    o[row * 1536 + 512 + hu] = f2b(c1[i]);
                    o[row * 1536 + 768 + hu] = f2b(h1v);
                    o[row * 1536 + 1024 + hu] = f2b(c2[i]);
                    o[row * 1536 + 1280 + hu] = f2b(h2v);
                } else {
                    float* o = (float*)outv;
                    o[row * 1536 + 0 + hu] = c0[i];
                    o[row * 1536 + 256 + hu] = h0v;
                    o[row * 1536 + 512 + hu] = c1[i];
                    o[row * 1536 + 768 + hu] = h1v;
                    o[row * 1536 + 1024 + hu] = c2[i];
                    o[row * 1536 + 1280 + hu] = h2v;
                }
            }
        }
    }
}

extern "C" void kernel_launch(void* const* d_in, const int* in_sizes, int n_in,
                              void* d_out, int out_size, void* d_ws, size_t ws_size,
                              hipStream_t stream) {
    const int* ids = (const int*)d_in[0];
    const void* emb = d_in[1];
    const void* W0x = d_in[2]; const void* W0h = d_in[3]; const void* b0 = d_in[4];
    const void* W1x = d_in[5]; const void* W1h = d_in[6]; const void* b1 = d_in[7];
    const void* W2x = d_in[8]; const void* W2h = d_in[9]; const void* b2 = d_in[10];
    char* ws = (char*)d_ws;

    long avail = (long)ws_size - O_AX;
    long per_t = 64L * 3072 * 2;
    int tc_single = (int)(avail / per_t);

    hipMemsetAsync(ws + O_SYNC, 0, 1572864, stream);
    hipMemsetAsync(ws + O_H, 0, 196608, stream);
    k_detect<<<1, 256, 0, stream>>>((const u32*)emb, (int*)(ws + O_FLAG));
    k_pack_a<<<384, 256, 0, stream>>>(W0x, W1x, W2x, d_ws);
    k_pack_r<<<640, 256, 0, stream>>>(W0h, W1x, W1h, W2x, W2h, d_ws);

    if (tc_single >= TSEQ) {
        // ---- single-dispatch mode: all Ax precomputed; no helper traffic during k_rec ----
        dim3 g(12, TSEQ);
        k_gemm_x<<<g, 256, 0, stream>>>(ids, emb, b0, b1, b2, d_ws, 0);
        k_rec<<<GRID_REC, 256, 0, stream>>>(ids, emb, b0, b1, b2, d_ws, d_out,
                                            0, 0, TSEQ, 0, 0, 0L, 1, 1);
        return;
    }

    // ---- chunked fallback (double-buffered Ax, helpers compute next chunk) ----
    int tc_max = (int)(avail / (2 * per_t));
    if (tc_max > TSEQ) tc_max = TSEQ;
    if (tc_max < 4) tc_max = 4;
    long axstride = (long)tc_max * 196608;
    int nck = (TSEQ + tc_max - 1) / tc_max;

    int tc0 = (TSEQ < tc_max) ? TSEQ : tc_max;
    { dim3 g(12, (unsigned)tc0);
      k_gemm_x<<<g, 256, 0, stream>>>(ids, emb, b0, b1, b2, d_ws, 0); }

    for (int c = 0; c < nck; ++c) {
        int t0 = c * tc_max;
        int tc = TSEQ - t0; if (tc > tc_max) tc = tc_max;
        int t0n = t0 + tc;
        int tcn = 0;
        if (c + 1 < nck) { tcn = TSEQ - t0n; if (tcn > tc_max) tcn = tc_max; }
        k_rec<<<GRID_REC, 256, 0, stream>>>(ids, emb, b0, b1, b2, d_ws, d_out,
                                            c, t0, tc, t0n, tcn, axstride,
                                            c == 0, t0 + tc == TSEQ);
    }
}

// Round 15
// 6196.625 us; speedup vs baseline: 1.1158x; 1.1158x over previous
//
#include <hip/hip_runtime.h>
#include <hip/hip_bf16.h>

// DeepLSTM on MI355X — R19: R17 base + Ax prefetch moved OFF flagB's publish edge.
//   R18 post-mortem: per-wave flags = slight regression (6.42 vs 6.20ms; flag traffic
//   x4 -> MALL contention; block s_barrier joins were cheap). Reverted to R17 protocol.
//   R17 schedule audit: Ax prefetch issued at P2-top is drained by flag_pub(flagB)'s
//   __syncthreads (vmcnt(0)) at P2-end — the R6/R15 drain bug reintroduced on the
//   TIGHTEST edge (flagB: pub'd end of step i, consumed ~1/3 into step i+1, slack ~
//   P3+P1). The cold-HBM Ax tail (~900cy) eats that slack.
//   R19: issue the prefetch AFTER flag_pub(flagB) (in P3, before the flagA wait). flagB
//   pub now drains only fast L2 h-stores; Ax loads ride through flagA poll + next P1 and
//   drain at the NEXT flagA pub — off every tight publish edge.
// Superstep s computes S0(t=s), S1(t=s-1), S2(t=s-2); reads parity s^1, writes parity s.

typedef __attribute__((ext_vector_type(8))) short short8;
typedef __attribute__((ext_vector_type(4))) float f32x4;
typedef unsigned short u16;
typedef unsigned int u32;

#define TSEQ 1000
#define NBLK 32
#define GRID_REC 256
#define NHELP (GRID_REC - NBLK)

// ws layout (bytes). Sync slot (per chunk, stride 6144): election @+0,
// flagA @+3072 (32 x u32), flagB @+3328 (32 x u32, separate lines).
#define O_FLAG 0L
#define O_SYNC 512L
#define O_H    1573376L  // h[3][2][4][8][64][8] bf16 = 196608 (fragment order)
#define O_C    1769984L  // c_save[3][64][256] f32 = 196608
#define O_BPA  1966592L  // packed phase-A B: 192 tiles * 8 ks * 64 lanes * 16B
#define O_BPR  3539456L  // packed rec B: 32 rank * 80 fb * 64 lanes * 16B
#define O_AX   6160896L  // Ax: single buffer (1000 t) or 2 chunked buffers ([t][3][32][64*32])

__device__ __forceinline__ u16 f2b(float v) {
    __hip_bfloat16 h = __float2bfloat16(v);
    u16 u; __builtin_memcpy(&u, &h, 2); return u;
}
__device__ __forceinline__ float b2f(u16 u) {
    __hip_bfloat16 h; __builtin_memcpy(&h, &u, 2); return __bfloat162float(h);
}
__device__ __forceinline__ float rdw(const void* p, long i, int isbf) {
    return isbf ? b2f(((const u16*)p)[i]) : ((const float*)p)[i];
}
__device__ __forceinline__ float sigm(float x) { return 1.0f / (1.0f + __expf(-x)); }
__device__ __forceinline__ float tanh_(float x) { return 1.0f - 2.0f / (1.0f + __expf(2.0f * x)); }
__device__ __forceinline__ f32x4 mfma16(short8 a, short8 b, f32x4 c) {
    return __builtin_amdgcn_mfma_f32_16x16x32_bf16(a, b, c, 0, 0, 0);
}

// ---------- dtype detect ----------
__global__ void k_detect(const u32* __restrict__ embw, int* flag) {
    __shared__ int cnt[256];
    int tid = threadIdx.x, c = 0;
    for (int i = 0; i < 16; ++i) {
        u32 w = embw[tid * 16 + i];
        u32 e = (w >> 7) & 0xFF;
        c += (e >= 110 && e <= 126) ? 1 : 0;
    }
    cnt[tid] = c; __syncthreads();
    for (int s = 128; s > 0; s >>= 1) { if (tid < s) cnt[tid] += cnt[tid + s]; __syncthreads(); }
    if (tid == 0) flag[0] = (cnt[0] > 2048) ? 1 : 0;
}

// ---------- pack phase-A B ----------
__global__ void k_pack_a(const void* W0x, const void* W1x, const void* W2x, void* wsv) {
    char* ws = (char*)wsv;
    int isbf = *(const int*)(ws + O_FLAG);
    int l = threadIdx.x & 63, w = threadIdx.x >> 6;
    int gid = blockIdx.x * 4 + w;          // 0..1535 = tile*8 + ks
    int tile = gid >> 3, ks = gid & 7;
    int L = tile >> 6, wi = tile & 63, bk = wi >> 1, half = wi & 1;
    int n16 = l & 15, g = half * 2 + (n16 >> 3), u = n16 & 7;
    int n = g * 256 + bk * 8 + u;
    const void* W = (L == 0) ? W0x : ((L == 1) ? W1x : W2x);
    union { u16 us[8]; short8 v; } tmp;
#pragma unroll
    for (int j = 0; j < 8; ++j) {
        int k = ks * 32 + (l >> 4) * 8 + j;
        tmp.us[j] = f2b(rdw(W, (long)k * 1024 + n, isbf));
    }
    ((short8*)(ws + O_BPA))[(long)(tile * 8 + ks) * 64 + l] = tmp.v;
}

// ---------- pack recurrent B ----------
__global__ void k_pack_r(const void* W0h, const void* W1x, const void* W1h,
                         const void* W2x, const void* W2h, void* wsv) {
    char* ws = (char*)wsv;
    int isbf = *(const int*)(ws + O_FLAG);
    int l = threadIdx.x & 63, w = threadIdx.x >> 6;
    int gid = blockIdx.x * 4 + w;          // 0..2559 = rank*80 + fb
    int bk = gid / 80, fb = gid % 80;
    int s, nt, ks;
    if (fb < 16) { s = 0; nt = fb >> 3; ks = fb & 7; }
    else if (fb < 48) { s = 1; int f = fb - 16; nt = f >> 4; ks = f & 15; }
    else { s = 2; int f = fb - 48; nt = f >> 4; ks = f & 15; }
    int n16 = l & 15, g = nt * 2 + (n16 >> 3), u = n16 & 7;
    int n = g * 256 + bk * 8 + u;
    union { u16 us[8]; short8 v; } tmp;
#pragma unroll
    for (int j = 0; j < 8; ++j) {
        int k = ks * 32 + (l >> 4) * 8 + j;
        float v;
        if (s == 0) v = rdw(W0h, (long)k * 1024 + n, isbf);
        else if (s == 1) v = (k < 256) ? rdw(W1x, (long)(256 + k) * 1024 + n, isbf)
                                       : rdw(W1h, (long)(k - 256) * 1024 + n, isbf);
        else v = (k < 256) ? rdw(W2x, (long)(256 + k) * 1024 + n, isbf)
                           : rdw(W2h, (long)(k - 256) * 1024 + n, isbf);
        tmp.us[j] = f2b(v);
    }
    ((short8*)(ws + O_BPR))[(long)bk * 80 * 64 + (long)fb * 64 + l] = tmp.v;
}

// ---------- x-GEMM tile: 64 batch rows x 256 gate cols at timestep t ----------
// Output layout (per t): [L(3)][rank(32)][row(64)*32 + half*16 + n16]  (4KB blocks)
__device__ __forceinline__ void gemm_tile(const int* __restrict__ ids, const void* __restrict__ emb,
    const void* b0, const void* b1, const void* b2, const short8* __restrict__ bpa,
    int isbf, int seg, int t, u16* __restrict__ axp) {
    int tid = threadIdx.x, l = tid & 63, w = tid >> 6;
    int n16 = l & 15, kg = l >> 4;
    short8 a[4][8];
#pragma unroll
    for (int mt = 0; mt < 4; ++mt) {
        int b = mt * 16 + n16;
        long id = ids[b * TSEQ + t];
        if (isbf) {
            const u16* ep = (const u16*)emb + id * 256;
#pragma unroll
            for (int ks = 0; ks < 8; ++ks)
                a[mt][ks] = *(const short8*)(ep + ks * 32 + kg * 8);
        } else {
            const float* ep = (const float*)emb + id * 256;
#pragma unroll
            for (int ks = 0; ks < 8; ++ks) {
                f32x4 v0 = *(const f32x4*)(ep + ks * 32 + kg * 8);
                f32x4 v1 = *(const f32x4*)(ep + ks * 32 + kg * 8 + 4);
                union { u16 us[8]; short8 v; } tmp;
#pragma unroll
                for (int j = 0; j < 4; ++j) { tmp.us[j] = f2b(v0[j]); tmp.us[4 + j] = f2b(v1[j]); }
                a[mt][ks] = tmp.v;
            }
        }
    }
#pragma unroll
    for (int nt = 0; nt < 4; ++nt) {
        int tile = seg * 16 + w * 4 + nt;
        f32x4 acc[4];
#pragma unroll
        for (int mt = 0; mt < 4; ++mt) acc[mt] = (f32x4){0.f, 0.f, 0.f, 0.f};
#pragma unroll
        for (int ks = 0; ks < 8; ++ks) {
            short8 bb = bpa[(long)(tile * 8 + ks) * 64 + l];
#pragma unroll
            for (int mt = 0; mt < 4; ++mt) acc[mt] = mfma16(a[mt][ks], bb, acc[mt]);
        }
        int L = tile >> 6, wi = tile & 63, bkk = wi >> 1, half = wi & 1;
        int g = half * 2 + (n16 >> 3), u = n16 & 7;
        const void* bias = (L == 0) ? b0 : ((L == 1) ? b1 : b2);
        float bv = rdw(bias, g * 256 + bkk * 8 + u, isbf);
        long base = (long)(L * 32 + bkk) * 2048 + half * 16 + n16;
#pragma unroll
        for (int mt = 0; mt < 4; ++mt)
#pragma unroll
            for (int i = 0; i < 4; ++i) {
                int row = mt * 16 + kg * 4 + i;
                axp[base + (long)row * 32] = f2b(acc[mt][i] + bv);
            }
    }
}

__global__ __launch_bounds__(256, 1) void k_gemm_x(
    const int* __restrict__ ids, const void* __restrict__ emb,
    const void* b0, const void* b1, const void* b2, void* wsv, int t0) {
    char* ws = (char*)wsv;
    int isbf = *(const int*)(ws + O_FLAG);
    const short8* bpa = (const short8*)(ws + O_BPA);
    u16* ax = (u16*)(ws + O_AX);   // buffer 0
    gemm_tile(ids, emb, b0, b1, b2, bpa, isbf, blockIdx.x, t0 + blockIdx.y,
              ax + (long)blockIdx.y * 196608);
}

// ---------- split-phase flags (agent-scope protocol, R8/R10-proven) ----------
// pub: __syncthreads drains each wave's vmcnt (stores in L2) before tid0 publishes.
// wait: wave0 polls its 32 flags; raw s_barrier (no drain) joins waves; buffer_inv
// gives acquire semantics for the subsequent h reads.
__device__ __forceinline__ void flag_pub(u32* f, int rank, u32 p, int tid) {
    __syncthreads();
    if (tid == 0)
        __hip_atomic_store(f + rank, p, __ATOMIC_RELAXED, __HIP_MEMORY_SCOPE_AGENT);
}
__device__ __forceinline__ void flag_wait(u32* f, u32 p, int l, int w) {
    if (w == 0) {
        u32* my = f + (l & 31);
        for (int it = 0; it < (1 << 20); ++it) {
            u32 v = __hip_atomic_load(my, __ATOMIC_RELAXED, __HIP_MEMORY_SCOPE_AGENT);
            if (__all((int)(v >= p))) break;
        }
    }
    __builtin_amdgcn_s_barrier();
    asm volatile("buffer_inv" ::: "memory");
}

// gate math, unified transcendentals (R15, proven). own lanes (n16<8): g0=i, g1=f.
// partner: g0=j, g1=o. Partner lanes compute tanh(j)/sigm(o) themselves; shfl RESULTS.
__device__ __forceinline__ void gate_update(f32x4 acc0, f32x4 acc1,
    const u32* ax0, const u32* ax1, float* cst, u16* hc, int hoff, bool own) {
    float A0 = own ? -1.0f : 2.0f;     // own: sigm(i)  partner: tanh(j)
    float C1 = own ? 1.0f : -2.0f;
    float C0 = own ? 0.0f : 1.0f;
#pragma unroll
    for (int i = 0; i < 4; ++i) {
        float g0 = acc0[i] + b2f((u16)ax0[i]);
        float g1 = acc1[i] + b2f((u16)ax1[i]);
        float v0 = C1 * (1.0f / (1.0f + __expf(A0 * g0))) + C0;  // sigm(i) | tanh(j)
        float v1 = 1.0f / (1.0f + __expf(-g1));                  // sigm(f) | sigm(o)
        float tj = __shfl_xor(v0, 8, 64);   // own receives tanh(j)
        float so = __shfl_xor(v1, 8, 64);   // own receives sigm(o)
        float cn = v1 * cst[i] + v0 * tj;   // own: sigm(f)*c + sigm(i)*tanh(j)
        float hn = so * tanh_(cn);          // own: sigm(o)*tanh(cn)
        cst[i] = own ? cn : 0.0f;
        if (own) hc[hoff + i * 8] = f2b(hn);
    }
}

// issue one stage's Ax slice as raw u16 loads (consumed next superstep)
__device__ __forceinline__ void loadax_raw(u32 dst[2][4], const u16* axs, int n16, int w, int kg) {
#pragma unroll
    for (int i = 0; i < 4; ++i) {
        int row = w * 16 + kg * 4 + i;
        dst[0][i] = axs[row * 32 + n16];
        dst[1][i] = axs[row * 32 + 16 + n16];
    }
}

// load one 16-row h slab (fragment order -> fully coalesced: lane l reads +l*8)
__device__ __forceinline__ void ldslab(short8 dst[8], const u16* hb, int w, int l) {
#pragma unroll
    for (int ks = 0; ks < 8; ++ks)
        dst[ks] = *(const short8*)(hb + w * 4096 + ks * 512 + l * 8);
}

// MFMA accumulation, B from LDS
__device__ __forceinline__ void acc8r(const short8 a[8], const short8* bq,
    int i0, int i1, int l, f32x4& a0, f32x4& a1) {
#pragma unroll
    for (int ks = 0; ks < 8; ++ks) {
        a0 = mfma16(a[ks], bq[(i0 + ks) * 64 + l], a0);
        a1 = mfma16(a[ks], bq[(i1 + ks) * 64 + l], a1);
    }
}

__global__ __launch_bounds__(256, 1) void k_rec(
    const int* __restrict__ ids, const void* __restrict__ emb,
    const void* b0, const void* b1, const void* b2,
    void* wsv, void* outv, int chunk, int t0, int tc, int t0n, int tcn,
    long axstride, int first, int last) {
    __shared__ short8 bq[4096];
    __shared__ int sh_role, sh_rank;
    char* ws = (char*)wsv;
    int tid = threadIdx.x, l = tid & 63, w = tid >> 6;
    int isbf = *(const int*)(ws + O_FLAG);
    char* slot = ws + O_SYNC + (long)chunk * 6144;
    int* syn = (int*)slot;
    u32* flagA = (u32*)(slot + 3072);
    u32* flagB = (u32*)(slot + 3328);
    // ---- census & election (once per dispatch; agent atomics OK here) ----
    if (tid == 0) {
        int xcc;
        asm volatile("s_getreg_b32 %0, hwreg(HW_REG_XCC_ID, 0, 8)" : "=s"(xcc));
        xcc &= 7;
        int r = __hip_atomic_fetch_add(syn + 2 + xcc, 1, __ATOMIC_RELAXED, __HIP_MEMORY_SCOPE_AGENT);
        int role = 1, rank = -1;
        if (r < NBLK) {
            if (r == NBLK - 1) {
                int exp = 0;
                __hip_atomic_compare_exchange_strong(syn + 10, &exp, xcc + 1,
                    __ATOMIC_RELAXED, __ATOMIC_RELAXED, __HIP_MEMORY_SCOPE_AGENT);
            }
            int wv;
            while ((wv = __hip_atomic_load(syn + 10, __ATOMIC_RELAXED, __HIP_MEMORY_SCOPE_AGENT)) == 0)
                __builtin_amdgcn_s_sleep(8);
            if (wv == xcc + 1) { role = 0; rank = r; }
        }
        if (role) rank = __hip_atomic_fetch_add(syn + 11, 1, __ATOMIC_RELAXED, __HIP_MEMORY_SCOPE_AGENT);
        sh_role = role; sh_rank = rank;
    }
    __syncthreads();
    int role = sh_role, rank = sh_rank;

    if (role) {   // ---- helper: next chunk's x-GEMM (chunked fallback mode only) ----
        asm volatile("s_setprio 0");
        if (tcn > 0) {
            const short8* bpa = (const short8*)(ws + O_BPA);
            u16* axn = (u16*)(ws + O_AX) + (long)((chunk + 1) & 1) * axstride;
            for (int job = rank; job < 12 * tcn; job += NHELP) {
                int seg = job % 12, tl = job / 12;
                gemm_tile(ids, emb, b0, b1, b2, bpa, isbf, seg, t0n + tl,
                          axn + (long)tl * 196608);
            }
        }
        return;
    }
    asm volatile("s_setprio 3");
    // ---- worker ----
    const short8* bpr = (const short8*)(ws + O_BPR) + (long)rank * 80 * 64;
#pragma unroll
    for (int i = 0; i < 16; ++i) bq[i * 256 + tid] = bpr[16 * 64 + i * 256 + tid];
    short8 w0a[8], w0b[8];
#pragma unroll
    for (int ks = 0; ks < 8; ++ks) { w0a[ks] = bpr[ks * 64 + l]; w0b[ks] = bpr[(8 + ks) * 64 + l]; }
    u16* hbuf = (u16*)(ws + O_H);
    float* csave = (float*)(ws + O_C);
    const u16* axc = (const u16*)(ws + O_AX) + (long)(chunk & 1) * axstride;
    int n16 = l & 15, kg = l >> 4;
    int hu = rank * 8 + (n16 & 7);
    bool own = n16 < 8;
    // fragment-layout store addressing
    int gbase = w * 4096 + (rank >> 2) * 512;          // [slab=w][ks_w=rank>>2]
    int hoff = (rank & 3) * 128 + kg * 32 + (n16 & 7); // lane' * 8 + j
    float c0[4], c1[4], c2[4];
#pragma unroll
    for (int i = 0; i < 4; ++i) {
        int row = w * 16 + kg * 4 + i;
        if (first || !own) { c0[i] = 0.f; c1[i] = 0.f; c2[i] = 0.f; }
        else {
            c0[i] = csave[(0 * 64 + row) * 256 + hu];
            c1[i] = csave[(1 * 64 + row) * 256 + hu];
            c2[i] = csave[(2 * 64 + row) * 256 + hu];
        }
    }
    __syncthreads();
    u32 lph = 0;
    const int sEnd = t0 + tc + 2;
    const int tEnd = t0 + tc;
    // ---- distance-1 pipelined Ax prefetch: RAW bf16 bits in pxA/pxB ping-pong ----
    u32 pxA[3][2][4], pxB[3][2][4];
    if (tc > 0) loadax_raw(pxA[0], axc + (long)rank * 2048, n16, w, kg);   // s=t0: only S0 active

// Per superstep (3 phases):
//   P1: ldslab h0; S0 MFMA + gates + h0 stores; pub flagA=lph+1   (early h0 publish)
//   P2: wait flagB>=lph (published END of prev step -> in flight P3+P1); ldslab h1,h2;
//       S1 + S2 MFMA + gates + stores; pub flagB=lph+1 (drains only fast L2 h-stores)
//   P3: issue next step's Ax prefetch (drained at NEXT flagA pub — off both publish
//       edges); wait flagA>=lph+1 (published ~2/3 step ago) [skip after last step]
#define SSTEP(CUR, NXT, S)                                                                         \
    do {                                                                                           \
        int par = (S) & 1, prv = par ^ 1;                                                          \
        const u16* h0p = hbuf + (0 * 2 + prv) * 16384; u16* h0c = hbuf + (0 * 2 + par) * 16384;    \
        const u16* h1p = hbuf + (1 * 2 + prv) * 16384; u16* h1c = hbuf + (1 * 2 + par) * 16384;    \
        const u16* h2p = hbuf + (2 * 2 + prv) * 16384; u16* h2c = hbuf + (2 * 2 + par) * 16384;    \
        bool l0 = (S) < tEnd, l1 = (S) > t0 && (S) <= tEnd, l2 = (S) > t0 + 1;                     \
        short8 a0r[8], a1r[8], a2r[8];                                                             \
        if (l0 || l1) ldslab(a0r, h0p, w, l);                                                      \
        if (l0) {                                                                                  \
            f32x4 A00 = {0.f, 0.f, 0.f, 0.f}, A01 = A00;                                           \
            _Pragma("unroll")                                                                      \
            for (int ks = 0; ks < 8; ++ks) {                                                       \
                A00 = mfma16(a0r[ks], w0a[ks], A00); A01 = mfma16(a0r[ks], w0b[ks], A01);          \
            }                                                                                      \
            gate_update(A00, A01, CUR[0][0], CUR[0][1], c0, h0c + gbase, hoff, own);               \
        }                                                                                          \
        flag_pub(flagA, rank, lph + 1, tid);                                                       \
        flag_wait(flagB, lph, l, w);                                                               \
        if (l1 || l2) ldslab(a1r, h1p, w, l);                                                      \
        if (l2)       ldslab(a2r, h2p, w, l);                                                      \
        if (l1) {                                                                                  \
            f32x4 A10 = {0.f, 0.f, 0.f, 0.f}, A11 = A10;                                           \
            acc8r(a0r, bq, 0, 16, l, A10, A11); acc8r(a1r, bq, 8, 24, l, A10, A11);                \
            gate_update(A10, A11, CUR[1][0], CUR[1][1], c1, h1c + gbase, hoff, own);               \
        }                                                                                          \
        if (l2) {                                                                                  \
            f32x4 A20 = {0.f, 0.f, 0.f, 0.f}, A21 = A20;                                           \
            acc8r(a1r, bq, 32, 48, l, A20, A21); acc8r(a2r, bq, 40, 56, l, A20, A21);              \
            gate_update(A20, A21, CUR[2][0], CUR[2][1], c2, h2c + gbase, hoff, own);               \
        }                                                                                          \
        flag_pub(flagB, rank, lph + 1, tid);                                                       \
        int q = (S) + 1;                                                                           \
        if (q < sEnd) {                                                                            \
            if (q < tEnd)                                                                          \
                loadax_raw(NXT[0], axc + (long)(q - t0) * 196608 + (long)rank * 2048, n16, w, kg); \
            if (q > t0 && q <= tEnd)                                                               \
                loadax_raw(NXT[1], axc + (long)(q - 1 - t0) * 196608 + (long)(32 + rank) * 2048, n16, w, kg); \
            if (q > t0 + 1)                                                                        \
                loadax_raw(NXT[2], axc + (long)(q - 2 - t0) * 196608 + (long)(64 + rank) * 2048, n16, w, kg); \
        }                                                                                          \
        ++lph;                                                                                     \
        if ((S) + 1 < sEnd) flag_wait(flagA, lph, l, w);                                           \
    } while (0)

    for (int s = t0; s < sEnd; ) {
        SSTEP(pxA, pxB, s); ++s; if (s >= sEnd) break;
        SSTEP(pxB, pxA, s); ++s;
    }
#undef SSTEP

    if (own) {
#pragma unroll
        for (int i = 0; i < 4; ++i) {
            int row = w * 16 + kg * 4 + i;
            csave[(0 * 64 + row) * 256 + hu] = c0[i];
            csave[(1 * 64 + row) * 256 + hu] = c1[i];
            csave[(2 * 64 + row) * 256 + hu] = c2[i];
        }
        if (last) {
            int f0 = (TSEQ - 1) & 1, f1 = TSEQ & 1, f2 = (TSEQ + 1) & 1;
#pragma unroll
            for (int i = 0; i < 4; ++i) {
                int row = w * 16 + kg * 4 + i;
                float h0v = b2f(hbuf[(0 * 2 + f0) * 16384 + gbase + hoff + i * 8]);
                float h1v = b2f(hbuf[(1 * 2 + f1) * 16384 + gbase + hoff + i * 8]);
                float h2v = b2f(hbuf[(2 * 2 + f2) * 16384 + gbase + hoff + i * 8]);
                if (isbf) {
                    u16* o = (u16*)outv;
                    o[row * 1536 + 0 + hu] = f2b(c0[i]);
                    o[row * 1536 + 256 + hu] = f2b(h0v);
                    o[row * 1536 + 512 + hu] = f2b(c1[i]);
                    o[row * 1536 + 768 + hu] = f2b(h1v);
                    o[row * 1536 + 1024 + hu] = f2b(c2[i]);
                    o[row * 1536 + 1280 + hu] = f2b(h2v);
                } else {
                    float* o = (float*)outv;
                    o[row * 1536 + 0 + hu] = c0[i];
                    o[row * 1536 + 256 + hu] = h0v;
                    o[row * 1536 + 512 + hu] = c1[i];
                    o[row * 1536 + 768 + hu] = h1v;
                    o[row * 1536 + 1024 + hu] = c2[i];
                    o[row * 1536 + 1280 + hu] = h2v;
                }
            }
        }
    }
}

extern "C" void kernel_launch(void* const* d_in, const int* in_sizes, int n_in,
                              void* d_out, int out_size, void* d_ws, size_t ws_size,
                              hipStream_t stream) {
    const int* ids = (const int*)d_in[0];
    const void* emb = d_in[1];
    const void* W0x = d_in[2]; const void* W0h = d_in[3]; const void* b0 = d_in[4];
    const void* W1x = d_in[5]; const void* W1h = d_in[6]; const void* b1 = d_in[7];
    const void* W2x = d_in[8]; const void* W2h = d_in[9]; const void* b2 = d_in[10];
    char* ws = (char*)d_ws;

    long avail = (long)ws_size - O_AX;
    long per_t = 64L * 3072 * 2;
    int tc_single = (int)(avail / per_t);

    hipMemsetAsync(ws + O_SYNC, 0, 1572864, stream);
    hipMemsetAsync(ws + O_H, 0, 196608, stream);
    k_detect<<<1, 256, 0, stream>>>((const u32*)emb, (int*)(ws + O_FLAG));
    k_pack_a<<<384, 256, 0, stream>>>(W0x, W1x, W2x, d_ws);
    k_pack_r<<<640, 256, 0, stream>>>(W0h, W1x, W1h, W2x, W2h, d_ws);

    if (tc_single >= TSEQ) {
        // ---- single-dispatch mode: all Ax precomputed; no helper traffic during k_rec ----
        dim3 g(12, TSEQ);
        k_gemm_x<<<g, 256, 0, stream>>>(ids, emb, b0, b1, b2, d_ws, 0);
        k_rec<<<GRID_REC, 256, 0, stream>>>(ids, emb, b0, b1, b2, d_ws, d_out,
                                            0, 0, TSEQ, 0, 0, 0L, 1, 1);
        return;
    }

    // ---- chunked fallback (double-buffered Ax, helpers compute next chunk) ----
    int tc_max = (int)(avail / (2 * per_t));
    if (tc_max > TSEQ) tc_max = TSEQ;
    if (tc_max < 4) tc_max = 4;
    long axstride = (long)tc_max * 196608;
    int nck = (TSEQ + tc_max - 1) / tc_max;

    int tc0 = (TSEQ < tc_max) ? TSEQ : tc_max;
    { dim3 g(12, (unsigned)tc0);
      k_gemm_x<<<g, 256, 0, stream>>>(ids, emb, b0, b1, b2, d_ws, 0); }

    for (int c = 0; c < nck; ++c) {
        int t0 = c * tc_max;
        int tc = TSEQ - t0; if (tc > tc_max) tc = tc_max;
        int t0n = t0 + tc;
        int tcn = 0;
        if (c + 1 < nck) { tcn = TSEQ - t0n; if (tcn > tc_max) tcn = tc_max; }
        k_rec<<<GRID_REC, 256, 0, stream>>>(ids, emb, b0, b1, b2, d_ws, d_out,
                                            c, t0, tc, t0n, tcn, axstride,
                                            c == 0, t0 + tc == TSEQ);
    }
}